// Round 8
// baseline (86.823 us; speedup 1.0000x reference)
//
#include <hip/hip_runtime.h>
#include <hip/hip_bf16.h>

typedef __attribute__((ext_vector_type(8))) short bf16x8;
typedef __attribute__((ext_vector_type(4))) float f32x4;

constexpr int NB = 16, CIN = 256, COUT = 256, TDIM = 4096, KS = 3, PADV = 1;
constexpr int TT = 128;            // t per block
constexpr int BK = 64;             // K-step (64 channels of one tap)
constexpr int NSTEP = 12;          // 4 c-blocks x 3 taps
constexpr int WSPAN = 144;         // x-window slots per c-block (t-halo +-8)

typedef __attribute__((address_space(1))) const unsigned int gu32;
typedef __attribute__((address_space(3))) unsigned int lu32;

static __device__ __forceinline__ ushort f2bf(float f) {
    union { __hip_bfloat16 h; ushort u; } cv;
    cv.h = __float2bfloat16(f);
    return cv.u;
}
static __device__ __forceinline__ float bf2f(ushort u) {
    union { unsigned int u32; float f; } cv;
    cv.u32 = ((unsigned int)u) << 16;
    return cv.f;
}

// Step s = cb*3 + k covers channels [cb*64, cb*64+64) of tap k. Per-step LDS
// image PRE-swizzled so a linear global_load_lds lands such that byte
// (o*128 + oc*16)^((o&7)<<4) holds W[o][tap k][c0 + oc*8 .. +8].
// (identical to round-6 prepack)
__global__ __launch_bounds__(256) void prepack_w(const float* __restrict__ w,
                                                 __hip_bfloat16* __restrict__ wp) {
    int idx = blockIdx.x * 256 + threadIdx.x;      // NSTEP*COUT*BK = 196608
    if (idx >= NSTEP * COUT * BK) return;
    int e  = idx & 7;
    int j  = (idx >> 3) & 7;
    int o  = (idx >> 6) & (COUT - 1);
    int s  = idx >> 14;                            // 0..11
    int k  = s % 3;
    int c  = (s / 3) * 64 + ((j ^ (o & 7)) << 3) + e;
    wp[idx] = __float2bfloat16(w[(o * CIN + c) * KS + k]);
}

__global__ __launch_bounds__(512, 4) void deform_mfma(
    const float* __restrict__ x,              // (NB, CIN, TDIM)
    const float* __restrict__ off,            // (NB, 2*KS, TDIM, 1)
    const __hip_bfloat16* __restrict__ wp,    // swizzled pack, 384 KB
    const float* __restrict__ bias,           // (COUT)
    float* __restrict__ out)                  // (NB, COUT, TDIM)
{
    __shared__ ushort w_s[COUT * BK];       // 32 KB, swizzled W image per step
    __shared__ ushort v_s[TT * BK];         // 16 KB, swizzled V tile
    __shared__ ushort xw[WSPAN * 64];       // 18 KB, TRANSPOSED x window [j][c]
    __shared__ int4   sP[KS][TT];           // {jj, wa, wb, base} per (k,t) 6 KB

    const int tid = threadIdx.x;

    // XCD-chunked bijective swizzle: XCD q (= bid%8) owns batches {2q, 2q+1}.
    const int bid  = blockIdx.x;           // 0..511
    const int q    = bid & 7;
    const int r    = bid >> 3;             // 0..63
    const int b    = 2 * q + (r >> 5);
    const int tt0  = (r & 31) * TT;
    const int win_lo = tt0 - 8;

    // ---- Phase A: per-(k,t) window index & pair-ordered interp weights ----
    if (tid < KS * TT) {
        int k = tid >> 7, j = tid & (TT - 1);
        int t = tt0 + j;
        float dyr = off[((b * 2 * KS + 2 * k) * TDIM) + t];
        float dxr = off[((b * 2 * KS + 2 * k + 1) * TDIM) + t];
        // mirror ref rounding: dy = dyr - (k-PAD) first, then py = (t0+k) + dy
        float dyk = dyr - (float)(k - PADV);
        float py  = (float)(t - PADV + k) + dyk;
        float i0f = floorf(py);
        float fr  = py - i0f;
        int i0 = (int)i0f, i1 = i0 + 1;
        float wx = fmaxf(0.0f, 1.0f - fabsf(dxr));
        float w0 = (1.0f - fr) * wx * ((i0 >= 0 && i0 < TDIM) ? 1.0f : 0.0f);
        float w1 = fr * wx * ((i1 >= 0 && i1 < TDIM) ? 1.0f : 0.0f);
        int base = min(max(i0, 0), TDIM - 2);
        // pair (p0,p1) = (x[base], x[base+1]); route w0/w1 onto it:
        bool iA = (i0 == base);
        float wa = iA ? w0 : ((i0 + 1 == base) ? w1 : 0.0f);  // coeff of p0
        float wb = iA ? w1 : ((i0 == base + 1) ? w0 : 0.0f);  // coeff of p1
        int4 p;
        p.x = base - win_lo;               // jj (may be out of [0,142] -> fallback)
        p.y = __float_as_int(wa);
        p.z = __float_as_int(wb);
        p.w = base;
        sP[k][j] = p;
    }

    const int wid    = tid >> 6;
    const int lane   = tid & 63;
    const int o_base = (wid >> 1) * 64;
    const int t_base = (wid & 1) * 64;
    const int lr     = lane & 15;
    const int lg     = lane >> 4;

    const int coct0 = tid >> 7;            // 0..3
    const int t     = tid & (TT - 1);
    const int vrow  = t * (BK * 2);
    const int vswz  = (t & 7) << 4;
    const int voff0 = (vrow + coct0 * 16) ^ vswz;
    const int voff1 = (vrow + (coct0 + 4) * 16) ^ vswz;

    // staging decomposition: thread owns channel pair {2*c2, 2*c2+1}, 9 j-slots
    const int c2 = tid >> 4;               // 0..31
    const int pp = tid & 15;

    f32x4 acc[4][4];
    #pragma unroll
    for (int i = 0; i < 4; ++i)
        #pragma unroll
        for (int j = 0; j < 4; ++j) acc[i][j] = (f32x4)0.0f;

    const float* xb = x + (size_t)b * CIN * TDIM;

    __syncthreads();   // sP visible

    for (int cb = 0; cb < 4; ++cb) {
        const int cbase = cb * 64;

        // ---- stage x window (once per c-block): transposed, swizzled ----
        {
            const float* xr0 = xb + (size_t)(cbase + 2 * c2) * TDIM;
            const float* xr1 = xr0 + TDIM;
            const int sw_base = (((c2 >> 2)) << 4) + (c2 & 3) * 4;  // slot/offset before j-XOR
            #pragma unroll
            for (int i = 0; i < 9; ++i) {
                int j  = pp + 16 * i;
                int a  = win_lo + j;
                int ac = min(max(a, 0), TDIM - 1);
                unsigned int u = (unsigned int)f2bf(xr0[ac]) |
                                 ((unsigned int)f2bf(xr1[ac]) << 16);
                int byte = j * 128 + (sw_base ^ ((j & 7) << 4));
                *(unsigned int*)((char*)xw + byte) = u;
            }
        }
        __syncthreads();   // xw(cb) visible

        for (int k = 0; k < 3; ++k) {
            const int s_idx = cb * 3 + k;

            // ---- stage W: direct global->LDS DMA, pre-swizzled source ----
            {
                const char* gbase = (const char*)wp + (size_t)s_idx * 32768 + wid * 4096 + lane * 16;
                char* lbase = (char*)w_s + wid * 4096;   // wave-uniform
                #pragma unroll
                for (int i = 0; i < 4; ++i)
                    __builtin_amdgcn_global_load_lds((gu32*)(gbase + i * 1024),
                                                     (lu32*)(lbase + i * 1024), 16, 0, 0);
            }

            // ---- v-compute: 4x ds_read_b128 from xw + interp + pack ----
            {
                int4 e = sP[k][t];
                int jj = e.x;
                float wa = __int_as_float(e.y), wb = __int_as_float(e.z);
                int jc = min(max(jj, 0), WSPAN - 2);    // safe LDS row
                int j0s = jc * 128, j1s = (jc + 1) * 128;
                int x0 = (jc & 7) << 4, x1 = ((jc + 1) & 7) << 4;
                bf16x8 a0 = *(const bf16x8*)((const char*)xw + (j0s + ((coct0 << 4) ^ x0)));
                bf16x8 a1 = *(const bf16x8*)((const char*)xw + (j1s + ((coct0 << 4) ^ x1)));
                bf16x8 b0 = *(const bf16x8*)((const char*)xw + (j0s + (((coct0 + 4) << 4) ^ x0)));
                bf16x8 b1 = *(const bf16x8*)((const char*)xw + (j1s + (((coct0 + 4) << 4) ^ x1)));
                if (__builtin_expect((unsigned)jj > (unsigned)(WSPAN - 2), 0)) {
                    // |dyr| > 7 (prob ~1e-6): rebuild pairs from global, exact
                    int base = e.w;
                    const float* xrA = xb + (size_t)(cbase + coct0 * 8) * TDIM;
                    const float* xrB = xrA + (size_t)32 * TDIM;
                    #pragma unroll
                    for (int i = 0; i < 8; ++i) {
                        a0[i] = (short)f2bf(xrA[base]);
                        a1[i] = (short)f2bf(xrA[base + 1]);
                        b0[i] = (short)f2bf(xrB[base]);
                        b1[i] = (short)f2bf(xrB[base + 1]);
                        xrA += TDIM; xrB += TDIM;
                    }
                }
                bf16x8 pk0, pk1;
                #pragma unroll
                for (int i = 0; i < 8; ++i) {
                    pk0[i] = (short)f2bf(bf2f((ushort)a0[i]) * wa + bf2f((ushort)a1[i]) * wb);
                    pk1[i] = (short)f2bf(bf2f((ushort)b0[i]) * wa + bf2f((ushort)b1[i]) * wb);
                }
                *(bf16x8*)((char*)v_s + voff0) = pk0;
                *(bf16x8*)((char*)v_s + voff1) = pk1;
            }

            __syncthreads();   // drains W-DMA (vmcnt) + ds writes; tiles ready

            // ---- MFMA: wave computes 64(o) x 64(t), K=64 ----
            #pragma unroll
            for (int kb = 0; kb < 2; ++kb) {
                const int kk = kb * 32 + lg * 8;
                bf16x8 bfr[4];
                #pragma unroll
                for (int nf = 0; nf < 4; ++nf) {
                    int tc = t_base + nf * 16 + lr;
                    int byte = (tc * (BK * 2) + kk * 2) ^ ((tc & 7) << 4);
                    bfr[nf] = *(const bf16x8*)((const char*)v_s + byte);
                }
                #pragma unroll
                for (int mf = 0; mf < 4; ++mf) {
                    int o  = o_base + mf * 16 + lr;
                    int byte = (o * (BK * 2) + kk * 2) ^ ((o & 7) << 4);
                    bf16x8 af = *(const bf16x8*)((const char*)w_s + byte);
                    #pragma unroll
                    for (int nf = 0; nf < 4; ++nf)
                        acc[mf][nf] = __builtin_amdgcn_mfma_f32_16x16x32_bf16(
                            af, bfr[nf], acc[mf][nf], 0, 0, 0);
                }
            }
            __syncthreads();   // all frag reads done -> next step may overwrite
        }
    }

    // ---- Epilogue: D col = lane&15 (t), row = (lane>>4)*4 + reg (o) ----
    #pragma unroll
    for (int mf = 0; mf < 4; ++mf) {
        #pragma unroll
        for (int r2 = 0; r2 < 4; ++r2) {
            int o = o_base + mf * 16 + lg * 4 + r2;
            float bv = bias[o];
            float* orow = out + (size_t)(b * COUT + o) * TDIM + tt0 + t_base;
            #pragma unroll
            for (int nf = 0; nf < 4; ++nf)
                orow[nf * 16 + lr] = acc[mf][nf][r2] + bv;
        }
    }
}

extern "C" void kernel_launch(void* const* d_in, const int* in_sizes, int n_in,
                              void* d_out, int out_size, void* d_ws, size_t ws_size,
                              hipStream_t stream) {
    const float* x    = (const float*)d_in[0];
    const float* off  = (const float*)d_in[1];
    const float* w    = (const float*)d_in[2];
    const float* bias = (const float*)d_in[3];
    float* out = (float*)d_out;
    __hip_bfloat16* wp = (__hip_bfloat16*)d_ws;   // 384 KB swizzled pack

    prepack_w<<<dim3((NSTEP * COUT * BK + 255) / 256), dim3(256), 0, stream>>>(w, wp);

    dim3 grid(512);
    deform_mfma<<<grid, dim3(512), 0, stream>>>(x, off, wp, bias, out);
}